// Round 7
// baseline (282.244 us; speedup 1.0000x reference)
//
#include <hip/hip_runtime.h>

#define HH 256
#define WW 256
#define SS 65536   // pixels per mask; also the background sentinel label
#define NM 128     // B*K masks
#define TRR 16     // rows per tile
#define NT2 16     // tiles per mask
#define SPT 1024   // slots per tile = worst-case 8-conn components in 16x256
#define SPM 16384  // slots per mask (16 tiles x 1024)

struct Meta {
  double dsum[NM];   // total sum of m per mask
  double dins[NM];   // sum of m inside suppressed bbox
  int h0[NM]; int h1[NM]; int w0[NM]; int w1[NM];      // chosen bbox, inclusive
  int bh0[NM]; int bh1[NM]; int bw0[NM]; int bw1[NM];  // background bbox
  int fg0[NM];       // is mask pixel 0 foreground
};

__global__ void k_meta_init(Meta* mt) {
  int i = threadIdx.x;
  if (i < NM) {
    mt->dsum[i] = 0.0; mt->dins[i] = 0.0; mt->fg0[i] = 0;
    mt->h0[i] = 1; mt->h1[i] = 0; mt->w0[i] = 1; mt->w1[i] = 0;
    mt->bh0[i] = HH; mt->bh1[i] = -1; mt->bw0[i] = WW; mt->bw1[i] = -1;
  }
}

// Find with plain-store path compression (ECL-CC). Safe concurrent with
// atomicMin linking: stored values are live ancestors; parent < child.
__device__ __forceinline__ int find_c(int* L, int x) {
  int p = L[x];
  if (p == x) return x;
  int root = p, q = L[root];
  while (q != root) { root = q; q = L[root]; }
  if (root != p) L[x] = root;
  return root;
}

// Link larger root -> smaller root: final root = min id. Compact-id order ==
// root-pixel-label order, preserving the reference's min-pixel-index label.
__device__ void unite(int* L, int a, int b) {
  bool done = false;
  do {
    a = find_c(L, a);
    b = find_c(L, b);
    if (a < b)      { int old = atomicMin(&L[b], a); done = (old == b); b = old; }
    else if (b < a) { int old = atomicMin(&L[a], b); done = (old == a); a = old; }
    else done = true;
  } while (!done);
}

// Path-halving find (static tree; races only lose compression).
__device__ __forceinline__ int find_halve(int* L, int x) {
  int p = L[x];
  while (p != x) {
    int gp = L[p];
    if (gp == p) return p;
    L[x] = gp;
    x = p; p = gp;
  }
  return x;
}

__device__ __forceinline__ int cid(const unsigned long long* rm,
                                   const int* wpre, int p) {
  int w = p >> 6, b = p & 63;
  return wpre[w] + (int)__popcll(rm[w] & (b ? ((1ull << b) - 1) : 0ull));
}

// One block = one 16x256 tile (4096 px, 8 px/thread). ~38 KB LDS ->
// 4 blocks/CU = 32 waves/CU (max occupancy) for the latency-bound UF.
__global__ __launch_bounds__(512)
void k_local(const float* __restrict__ in, int cb,
             int* __restrict__ gp, int* __restrict__ ga, int* __restrict__ gl,
             int* __restrict__ gh0, int* __restrict__ gh1,
             int* __restrict__ gw0, int* __restrict__ gw1,
             int* __restrict__ gbrow, int* __restrict__ gnr,
             Meta* __restrict__ mt) {
  __shared__ int slab[4096];                      // 16 KB
  __shared__ unsigned long long sfgw[TRR][4];     // fg row bitmasks
  __shared__ unsigned char sfgc[TRR][32];         // 8-bit fg chunks
  __shared__ unsigned long long rm[64];           // root bitmask (4096 bits)
  __shared__ int wpre[64];                        // word-exclusive root prefix
  __shared__ int snr;
  __shared__ int sA[SPT], sW0[SPT], sW1[SPT], sH0[SPT], sH1[SPT];  // 20 KB
  __shared__ double sred[8];
  __shared__ int sbb[4][8];

  int q = blockIdx.x, lm = q >> 4, tile = q & 15;
  int tid = threadIdx.x, lane = tid & 63, wv = tid >> 6;
  int gm = cb + lm, R0 = tile << 4;

  // P1: load input (8 contiguous px/thread), m, dsum, fg bits.
  int r1 = tid >> 5, cs = tid & 31;
  const float4* src =
      (const float4*)(in + ((size_t)gm << 16) + ((R0 + r1) << 8) + (cs << 3));
  double dsum = 0.0;
  unsigned int fgb = 0;
  for (int k = 0; k < 2; k++) {
    float4 v = src[k];
    float m0 = fmaxf((v.x + 1.0f) * 0.5f, 0.0f);
    float m1 = fmaxf((v.y + 1.0f) * 0.5f, 0.0f);
    float m2 = fmaxf((v.z + 1.0f) * 0.5f, 0.0f);
    float m3 = fmaxf((v.w + 1.0f) * 0.5f, 0.0f);
    dsum += (double)m0 + (double)m1 + (double)m2 + (double)m3;
    fgb |= ((m0 > 0.5f) ? 1u : 0u) << (4 * k);
    fgb |= ((m1 > 0.5f) ? 1u : 0u) << (4 * k + 1);
    fgb |= ((m2 > 0.5f) ? 1u : 0u) << (4 * k + 2);
    fgb |= ((m3 > 0.5f) ? 1u : 0u) << (4 * k + 3);
  }
  sfgc[r1][cs] = (unsigned char)fgb;
  __syncthreads();
  if (tid < 64) {   // 16 rows x 4 words
    int row = tid >> 2, w = tid & 3;
    const unsigned char* pc = &sfgc[row][w << 3];
    unsigned long long wd = 0;
    for (int i = 0; i < 8; i++) wd |= ((unsigned long long)pc[i]) << (i << 3);
    sfgw[row][w] = wd;
  }
  __syncthreads();

  // P2: slab init with run-start labels (clz on row bitmask).
  // p = tid + 512*j: a wave's 64 lanes are 64 consecutive px in one row ->
  // conflict-free slab banking + ballot root enumeration.
  for (int j = 0; j < 8; j++) {
    int p = tid + (j << 9);
    int row = p >> 8, c = p & 255;
    const unsigned long long* Wr = sfgw[row];
    int lab = 0x7FFFFFFF;
    if ((Wr[c >> 6] >> (c & 63)) & 1) {
      int b = c & 63, w = c >> 6;
      unsigned long long z = ~Wr[w] & (b ? ((1ull << b) - 1) : 0ull);
      int w2 = w;
      while (z == 0 && w2 > 0) { w2--; z = ~Wr[w2]; }
      int start = z ? ((w2 << 6) + 63 - (int)__clzll(z) + 1) : 0;
      lab = (row << 8) + start;
    }
    slab[p] = lab;
  }
  __syncthreads();

  // P3: vertical unions with leftmost-contact dedup (all LDS).
  for (int j = 0; j < 8; j++) {
    int p = tid + (j << 9);
    int row = p >> 8, c = p & 255;
    if (row == 0) continue;
    const unsigned long long* Wr = sfgw[row];
    const unsigned long long* Wn = sfgw[row - 1];
    if (!((Wr[c >> 6] >> (c & 63)) & 1)) continue;
    bool wfg = (c > 0) && ((Wr[(c - 1) >> 6] >> ((c - 1) & 63)) & 1);
    bool nfg = (Wn[c >> 6] >> (c & 63)) & 1;
    if (!wfg) {
      if (nfg) unite(slab, p, p - 256);
      else if (c > 0 && ((Wn[(c - 1) >> 6] >> ((c - 1) & 63)) & 1))
        unite(slab, p, p - 257);
    }
    if (!nfg && c < 255 && ((Wn[(c + 1) >> 6] >> ((c + 1) & 63)) & 1))
      unite(slab, p, p - 255);
  }
  __syncthreads();

  // P4: resolve roots; ballot-built root bitmask (word w = wv + 8j).
  int rt[8];
  for (int j = 0; j < 8; j++) {
    int p = tid + (j << 9);
    int v = slab[p];
    int rr = -1;
    if (v != 0x7FFFFFFF) rr = find_halve(slab, p);
    rt[j] = rr;
    unsigned long long bal = __ballot(rr == p);
    if (lane == 0) rm[wv + (j << 3)] = bal;
  }
  __syncthreads();

  // Wave 0: exclusive word-prefix of root counts. Others: init stats.
  if (tid < 64) {
    int pa = (int)__popcll(rm[tid]);
    int sa = pa;
    for (int off = 1; off < 64; off <<= 1) {
      int ta = __shfl_up(sa, off); if (tid >= off) sa += ta;
    }
    wpre[tid] = sa - pa;
    if (tid == 63) snr = sa;
  } else {
    for (int s = tid - 64; s < SPT; s += 448) {
      sA[s] = 0; sW0[s] = WW; sW1[s] = -1; sH0[s] = TRR; sH1[s] = -1;
    }
  }
  __syncthreads();

  // P5: per-root stats via wave-aggregated LDS atomics; bg bbox in registers.
  int bw0r = WW, bw1r = -1, bh0r = TRR, bh1r = -1;
  for (int j = 0; j < 8; j++) {
    int p = tid + (j << 9);
    int row = p >> 8, c = p & 255;
    int rr = rt[j];
    if (rr < 0) {
      bw0r = min(bw0r, c); bw1r = max(bw1r, c);
      bh0r = min(bh0r, row); bh1r = max(bh1r, row);
    }
    int wc0 = c - lane;  // wave window base col
    bool pend = rr >= 0;
    while (__any(pend)) {
      unsigned long long mk = __ballot(pend);
      int srcl = (int)__ffsll(mk) - 1;
      int lead = __shfl(rr, srcl);
      bool mine = pend && (rr == lead);
      unsigned long long grp = __ballot(mine);
      if (lane == srcl) {
        int id = cid(rm, wpre, lead);
        int lo = (int)__ffsll(grp) - 1;
        int hi = 63 - (int)__clzll(grp);
        atomicAdd(&sA[id], (int)__popcll(grp));
        atomicMin(&sW0[id], wc0 + lo);
        atomicMax(&sW1[id], wc0 + hi);
        atomicMin(&sH0[id], row);
        atomicMax(&sH1[id], row);
      }
      pend = pend && !mine;
    }
  }
  __syncthreads();

  // P6: emit compact root records + seam boundary maps.
  int base = q << 10;
  for (int j = 0; j < 8; j++) {
    int p = tid + (j << 9);
    int row = p >> 8, c = p & 255;
    int rr = rt[j];
    if (rr == p) {
      int id = cid(rm, wpre, p);
      int gid = base + id;
      gp[gid] = gid;
      ga[gid] = sA[id];
      gl[gid] = (tile << 12) + p;       // root's mask-pixel index (the label)
      gw0[gid] = sW0[id]; gw1[gid] = sW1[id];
      gh0[gid] = R0 + sH0[id]; gh1[gid] = R0 + sH1[id];
    }
    if (row == 0 || row == TRR - 1) {
      int bi = (q << 9) + ((row == TRR - 1) ? 256 : 0) + c;
      gbrow[bi] = (rr >= 0) ? (base + cid(rm, wpre, rr)) : -1;
    }
  }
  if (tid == 0) gnr[q] = snr;

  // bg bbox + dsum block reductions.
  for (int off = 32; off > 0; off >>= 1) {
    bw0r = min(bw0r, __shfl_down(bw0r, off));
    bw1r = max(bw1r, __shfl_down(bw1r, off));
    bh0r = min(bh0r, __shfl_down(bh0r, off));
    bh1r = max(bh1r, __shfl_down(bh1r, off));
  }
  if (lane == 0) { sbb[0][wv] = bw0r; sbb[1][wv] = bw1r;
                   sbb[2][wv] = bh0r; sbb[3][wv] = bh1r; }
  for (int off = 32; off > 0; off >>= 1) dsum += __shfl_down(dsum, off);
  if (lane == 0) sred[wv] = dsum;
  __syncthreads();
  if (tid == 0) {
    int a0 = sbb[0][0], a1 = sbb[1][0], a2 = sbb[2][0], a3 = sbb[3][0];
    for (int i = 1; i < 8; i++) {
      a0 = min(a0, sbb[0][i]); a1 = max(a1, sbb[1][i]);
      a2 = min(a2, sbb[2][i]); a3 = max(a3, sbb[3][i]);
    }
    if (a1 >= 0) {
      atomicMin(&mt->bw0[gm], a0); atomicMax(&mt->bw1[gm], a1);
      atomicMin(&mt->bh0[gm], R0 + a2); atomicMax(&mt->bh1[gm], R0 + a3);
    }
    double t = 0.0;
    for (int i = 0; i < 8; i++) t += sred[i];
    atomicAdd(&mt->dsum[gm], t);
    if (tile == 0) mt->fg0[gm] = (int)(sfgw[0][0] & 1ull);
  }
}

// One block per mask: seam unions (15 seams) -> stats push -> exact top-2 ->
// bbox pick. All state is this mask's compact records: no cross-block deps;
// __syncthreads orders the phases.
__global__ __launch_bounds__(1024)
void k_mask(int* __restrict__ gp, int* __restrict__ ga,
            const int* __restrict__ gl,
            int* __restrict__ gh0, int* __restrict__ gh1,
            int* __restrict__ gw0, int* __restrict__ gw1,
            const int* __restrict__ gbrow, const int* __restrict__ gnr,
            Meta* __restrict__ mt, int c0) {
  int lm = blockIdx.x, gm = c0 + lm;
  int tid = threadIdx.x;
  int tb = lm << 4;           // first tile of this mask
  int sbase = lm << 14;

  // Phase A: seam unions on compact ids.
  for (int idx = tid; idx < 15 * 256; idx += 1024) {
    int s = idx >> 8, c = idx & 255;
    int tUp = tb + s;
    const int* up = gbrow + (tUp << 9) + 256;   // bottom row of upper tile
    const int* lo = gbrow + ((tUp + 1) << 9);   // top row of lower tile
    int v = lo[c];
    if (v < 0) continue;
    bool wfg = (c > 0) && (lo[c - 1] >= 0);
    int n = up[c];
    if (!wfg) {
      if (n >= 0) unite(gp, v, n);
      else if (c > 0) { int nw = up[c - 1]; if (nw >= 0) unite(gp, v, nw); }
    }
    if (n < 0 && c < 255) { int ne = up[c + 1]; if (ne >= 0) unite(gp, v, ne); }
  }
  __syncthreads();

  // Phase B: push non-final-root stats into final roots.
  for (int s = tid; s < SPM; s += 1024) {
    if ((s & (SPT - 1)) >= gnr[tb + (s >> 10)]) continue;
    int i = sbase + s;
    int r = find_c(gp, i);
    if (r != i) {
      atomicAdd(&ga[r], ga[i]);
      atomicMin(&gh0[r], gh0[i]); atomicMax(&gh1[r], gh1[i]);
      atomicMin(&gw0[r], gw0[i]); atomicMax(&gw1[r], gw1[i]);
    }
  }
  __syncthreads();

  // Phase C: top-2 with exact lax.top_k candidate set.
  // key = (area<<37)|((SS-lab)<<20)|slot : (area desc, label asc); slot bits
  // never decide order (labels distinct).
  unsigned long long t1 = 0, t2 = 0;
  int fsum = 0;
  for (int s = tid; s < SPM; s += 1024) {
    if ((s & (SPT - 1)) >= gnr[tb + (s >> 10)]) continue;
    int gid = sbase + s;
    if (gp[gid] == gid) {
      int a = ga[gid], lab = gl[gid];
      fsum += a;
      unsigned long long key = ((unsigned long long)a << 37)
                             | ((unsigned long long)(SS - lab) << 20)
                             | (unsigned)s;
      if (key > t1) { t2 = t1; t1 = key; }
      else if (key > t2) t2 = key;
    }
  }
  for (int off = 32; off > 0; off >>= 1) {
    unsigned long long o1 = __shfl_down(t1, off), o2 = __shfl_down(t2, off);
    if (o1 > t1) { t2 = (t1 > o2) ? t1 : o2; t1 = o1; }
    else if (o1 > t2) t2 = o1;
    fsum += __shfl_down(fsum, off);
  }
  __shared__ unsigned long long s1[16], s2[16];
  __shared__ int sf[16];
  int wv = tid >> 6, lane = tid & 63;
  if (lane == 0) { s1[wv] = t1; s2[wv] = t2; sf[wv] = fsum; }
  __syncthreads();
  if (tid == 0) {
    t1 = s1[0]; t2 = s2[0]; fsum = sf[0];
    for (int i = 1; i < 16; i++) {
      unsigned long long o1 = s1[i], o2 = s2[i];
      if (o1 > t1) { t2 = (t1 > o2) ? t1 : o2; t1 = o1; }
      else if (o1 > t2) t2 = o1;
      fsum += sf[i];
    }
    // background: label SS, area = SS - fg count
    unsigned long long bg = ((unsigned long long)(SS - fsum)) << 37;
    // best zero-area label: 0 if pixel0 is bg else 1 (px0/px1 are adjacent,
    // so at most one of {0,1} can be a root label; the smaller non-root wins)
    int zl = mt->fg0[gm] ? 1 : 0;
    unsigned long long zk = ((unsigned long long)(SS - zl)) << 20;
    if (bg > t1) { t2 = t1; t1 = bg; } else if (bg > t2) t2 = bg;
    if (zk > t1) { t2 = t1; t1 = zk; } else if (zk > t2) t2 = zk;
    int h0, h1, w0, w1;
    if (t2 == bg) {
      h0 = mt->bh0[gm]; h1 = mt->bh1[gm]; w0 = mt->bw0[gm]; w1 = mt->bw1[gm];
    } else if (t2 == zk) {
      h0 = 1; h1 = 0; w0 = 1; w1 = 0;   // empty bbox
    } else {
      int gid = sbase + (int)(t2 & 0xFFFFF);
      h0 = gh0[gid]; h1 = gh1[gid]; w0 = gw0[gid]; w1 = gw1[gid];
    }
    mt->h0[gm] = h0; mt->h1[gm] = h1; mt->w0[gm] = w0; mt->w1[gm] = w1;
  }
}

// 8 blocks per mask over the bbox rows; double partials into dins.
__global__ void k_inside(const float* __restrict__ in, Meta* __restrict__ mt,
                         int c0) {
  int b = blockIdx.x;
  int lm = b >> 3, seg = b & 7;
  int gm = c0 + lm;
  int h0 = mt->h0[gm], h1 = mt->h1[gm], w0 = mt->w0[gm], w1 = mt->w1[gm];
  double acc = 0.0;
  if (h1 >= h0) {
    int cc = w0 + threadIdx.x;
    if (cc <= w1) {
      const float* base = in + ((size_t)gm << 16);
      for (int rr = h0 + seg; rr <= h1; rr += 8) {
        float x = base[(rr << 8) + cc];
        acc += (double)fmaxf((x + 1.0f) * 0.5f, 0.0f);
      }
    }
  }
  for (int off = 32; off > 0; off >>= 1) acc += __shfl_down(acc, off);
  __shared__ double sd[4];
  int wid = threadIdx.x >> 6, lane = threadIdx.x & 63;
  if (lane == 0) sd[wid] = acc;
  __syncthreads();
  if (threadIdx.x == 0) {
    double t = sd[0] + sd[1] + sd[2] + sd[3];
    if (t != 0.0) atomicAdd(&mt->dins[gm], t);
  }
}

__global__ void k_final(const Meta* __restrict__ mt, float* __restrict__ out) {
  __shared__ double sd[NM];
  int t = threadIdx.x;
  sd[t] = (mt->dsum[t] - mt->dins[t]) / (double)SS;
  __syncthreads();
  for (int off = 64; off > 0; off >>= 1) {
    if (t < off) sd[t] += sd[t + off];
    __syncthreads();
  }
  if (t == 0) out[0] = (float)(sd[0] / (double)NM);
}

extern "C" void kernel_launch(void* const* d_in, const int* in_sizes, int n_in,
                              void* d_out, int out_size, void* d_ws,
                              size_t ws_size, hipStream_t stream) {
  const float* in = (const float*)d_in[0];
  float* out = (float*)d_out;

  Meta* mt = (Meta*)d_ws;
  const size_t meta_bytes = (sizeof(Meta) + 255) & ~(size_t)255;
  char* base = (char*)d_ws + meta_bytes;
  size_t avail = (ws_size > meta_bytes) ? (ws_size - meta_bytes) : 0;
  // per-mask: 7 compact arrays x 16384 slots + 16 tiles x 512 boundary + 16
  const size_t per_mask = (size_t)(7 * SPM + NT2 * 512 + NT2) * sizeof(int);
  int chunk = (int)(avail / per_mask);
  if (chunk > NM) chunk = NM;
  if (chunk < 1) return;  // insufficient workspace (would fail validation)

  int* gp    = (int*)base;
  int* ga    = gp  + (size_t)chunk * SPM;
  int* gl    = ga  + (size_t)chunk * SPM;
  int* gh0   = gl  + (size_t)chunk * SPM;
  int* gh1   = gh0 + (size_t)chunk * SPM;
  int* gw0   = gh1 + (size_t)chunk * SPM;
  int* gw1   = gw0 + (size_t)chunk * SPM;
  int* gbrow = gw1 + (size_t)chunk * SPM;
  int* gnr   = gbrow + (size_t)chunk * NT2 * 512;

  k_meta_init<<<1, 128, 0, stream>>>(mt);
  for (int c0 = 0; c0 < NM; c0 += chunk) {
    int cn = (chunk < NM - c0) ? chunk : (NM - c0);
    k_local<<<cn * NT2, 512, 0, stream>>>(in, c0, gp, ga, gl, gh0, gh1, gw0,
                                          gw1, gbrow, gnr, mt);
    k_mask <<<cn, 1024, 0, stream>>>(gp, ga, gl, gh0, gh1, gw0, gw1, gbrow,
                                     gnr, mt, c0);
    k_inside<<<cn * 8, 256, 0, stream>>>(in, mt, c0);
  }
  k_final<<<1, 128, 0, stream>>>(mt, out);
}

// Round 8
// 260.869 us; speedup vs baseline: 1.0819x; 1.0819x over previous
//
#include <hip/hip_runtime.h>

#define HH 256
#define WW 256
#define SS 65536   // pixels per mask; also the background sentinel label
#define NM 128     // B*K masks
#define TRR 16     // rows per tile
#define NT2 16     // tiles per mask
#define SPT 1024   // slots per tile = worst-case 8-conn components in 16x256
#define SPM 16384  // slots per mask (16 tiles x 1024)

struct Meta {
  double dsum[NM];   // total sum of m per mask
  double dins[NM];   // sum of m inside suppressed bbox
  int h0[NM]; int h1[NM]; int w0[NM]; int w1[NM];      // chosen bbox, inclusive
  int bh0[NM]; int bh1[NM]; int bw0[NM]; int bw1[NM];  // background bbox
  int fg0[NM];       // is mask pixel 0 foreground
};

__global__ void k_meta_init(Meta* mt) {
  int i = threadIdx.x;
  if (i < NM) {
    mt->dsum[i] = 0.0; mt->dins[i] = 0.0; mt->fg0[i] = 0;
    mt->h0[i] = 1; mt->h1[i] = 0; mt->w0[i] = 1; mt->w1[i] = 0;
    mt->bh0[i] = HH; mt->bh1[i] = -1; mt->bw0[i] = WW; mt->bw1[i] = -1;
  }
}

// Find with plain-store path compression (ECL-CC). Safe concurrent with
// atomicMin linking: stored values are live ancestors; parent < child.
__device__ __forceinline__ int find_c(int* L, int x) {
  int p = L[x];
  if (p == x) return x;
  int root = p, q = L[root];
  while (q != root) { root = q; q = L[root]; }
  if (root != p) L[x] = root;
  return root;
}

// Link larger root -> smaller root: final root = min id. Compact-id order ==
// root-pixel-label order, preserving the reference's min-pixel-index label.
__device__ void unite(int* L, int a, int b) {
  bool done = false;
  do {
    a = find_c(L, a);
    b = find_c(L, b);
    if (a < b)      { int old = atomicMin(&L[b], a); done = (old == b); b = old; }
    else if (b < a) { int old = atomicMin(&L[a], b); done = (old == a); a = old; }
    else done = true;
  } while (!done);
}

// Path-halving find (static tree; races only lose compression).
__device__ __forceinline__ int find_halve(int* L, int x) {
  int p = L[x];
  while (p != x) {
    int gp = L[p];
    if (gp == p) return p;
    L[x] = gp;
    x = p; p = gp;
  }
  return x;
}

__device__ __forceinline__ int cid(const unsigned long long* rm,
                                   const int* wpre, int p) {
  int w = p >> 6, b = p & 63;
  return wpre[w] + (int)__popcll(rm[w] & (b ? ((1ull << b) - 1) : 0ull));
}

// One block = one 16x256 tile (4096 px, 8 px/thread). Run-based stats: finds
// and LDS atomics happen per horizontal run (~2/thread), not per pixel.
__global__ __launch_bounds__(512)
void k_local(const float* __restrict__ in, int cb,
             int* __restrict__ gp, int* __restrict__ ga,
             unsigned int* __restrict__ gbb, unsigned short* __restrict__ gl,
             unsigned short* __restrict__ gbrow, int* __restrict__ gnr,
             Meta* __restrict__ mt) {
  __shared__ int slab[4096];                      // 16 KB
  __shared__ unsigned long long sfgw[TRR][4];     // fg row bitmasks
  __shared__ unsigned char sfgc[TRR][32];
  __shared__ unsigned long long rm[64];           // root bitmask (4096 bits)
  __shared__ int wpre[64];                        // word-exclusive root prefix
  __shared__ int snr;
  __shared__ int sA[SPT], sW0[SPT], sW1[SPT], sH0[SPT], sH1[SPT];  // 20 KB
  __shared__ double sred[8];
  __shared__ int sbb[4][8];

  int q = blockIdx.x, lm = q >> 4, tile = q & 15;
  int tid = threadIdx.x, lane = tid & 63, wv = tid >> 6;
  int gm = cb + lm, R0 = tile << 4;

  // P1: load input (8 contiguous px/thread), m, dsum, fg bits.
  int r1 = tid >> 5, cs = tid & 31;
  const float4* src =
      (const float4*)(in + ((size_t)gm << 16) + ((R0 + r1) << 8) + (cs << 3));
  double dsum = 0.0;
  unsigned int fgb = 0;
  for (int k = 0; k < 2; k++) {
    float4 v = src[k];
    float m0 = fmaxf((v.x + 1.0f) * 0.5f, 0.0f);
    float m1 = fmaxf((v.y + 1.0f) * 0.5f, 0.0f);
    float m2 = fmaxf((v.z + 1.0f) * 0.5f, 0.0f);
    float m3 = fmaxf((v.w + 1.0f) * 0.5f, 0.0f);
    dsum += (double)m0 + (double)m1 + (double)m2 + (double)m3;
    fgb |= ((m0 > 0.5f) ? 1u : 0u) << (4 * k);
    fgb |= ((m1 > 0.5f) ? 1u : 0u) << (4 * k + 1);
    fgb |= ((m2 > 0.5f) ? 1u : 0u) << (4 * k + 2);
    fgb |= ((m3 > 0.5f) ? 1u : 0u) << (4 * k + 3);
  }
  sfgc[r1][cs] = (unsigned char)fgb;
  __syncthreads();
  if (tid < 64) {   // 16 rows x 4 words
    int row = tid >> 2, w = tid & 3;
    const unsigned char* pc = &sfgc[row][w << 3];
    unsigned long long wd = 0;
    for (int i = 0; i < 8; i++) wd |= ((unsigned long long)pc[i]) << (i << 3);
    sfgw[row][w] = wd;
  }
  __syncthreads();

  // P2: slab init with run-start labels. p = tid + 512*j -> wave lanes are 64
  // consecutive px in one row: conflict-free banking, ballot root enumeration.
  for (int j = 0; j < 8; j++) {
    int p = tid + (j << 9);
    int row = p >> 8, c = p & 255;
    const unsigned long long* Wr = sfgw[row];
    int lab = 0x7FFFFFFF;
    if ((Wr[c >> 6] >> (c & 63)) & 1) {
      int b = c & 63, w = c >> 6;
      unsigned long long z = ~Wr[w] & (b ? ((1ull << b) - 1) : 0ull);
      int w2 = w;
      while (z == 0 && w2 > 0) { w2--; z = ~Wr[w2]; }
      int start = z ? ((w2 << 6) + 63 - (int)__clzll(z) + 1) : 0;
      lab = (row << 8) + start;
    }
    slab[p] = lab;
  }
  __syncthreads();

  // P3: vertical unions with leftmost-contact dedup (all LDS).
  for (int j = 0; j < 8; j++) {
    int p = tid + (j << 9);
    int row = p >> 8, c = p & 255;
    if (row == 0) continue;
    const unsigned long long* Wr = sfgw[row];
    const unsigned long long* Wn = sfgw[row - 1];
    if (!((Wr[c >> 6] >> (c & 63)) & 1)) continue;
    bool wfg = (c > 0) && ((Wr[(c - 1) >> 6] >> ((c - 1) & 63)) & 1);
    bool nfg = (Wn[c >> 6] >> (c & 63)) & 1;
    if (!wfg) {
      if (nfg) unite(slab, p, p - 256);
      else if (c > 0 && ((Wn[(c - 1) >> 6] >> ((c - 1) & 63)) & 1))
        unite(slab, p, p - 257);
    }
    if (!nfg && c < 255 && ((Wn[(c + 1) >> 6] >> ((c + 1) & 63)) & 1))
      unite(slab, p, p - 255);
  }
  __syncthreads();

  // P4: root bitmask via parent==self ballot (no finds needed).
  for (int j = 0; j < 8; j++) {
    int p = tid + (j << 9);
    unsigned long long bal = __ballot(slab[p] == p);
    if (lane == 0) rm[wv + (j << 3)] = bal;
  }
  __syncthreads();

  // Wave 0: exclusive word-prefix of root counts. Others: zero stats.
  if (tid < 64) {
    int pa = (int)__popcll(rm[tid]);
    int sa = pa;
    for (int off = 1; off < 64; off <<= 1) {
      int ta = __shfl_up(sa, off); if (tid >= off) sa += ta;
    }
    wpre[tid] = sa - pa;
    if (tid == 63) snr = sa;
  } else {
    for (int s = tid - 64; s < SPT; s += 448) {
      sA[s] = 0; sW0[s] = WW; sW1[s] = -1; sH0[s] = TRR; sH1[s] = -1;
    }
  }
  __syncthreads();

  // P5: per-RUN stats. Thread owns column c across 8 rows; at each run start
  // it computes the run length from the bitmask and does 5 LDS atomics.
  int c = tid & 255, rb = tid >> 8;
  bool anybg = false;
  int bh0r = TRR, bh1r = -1;
  for (int j = 0; j < 8; j++) {
    int row = rb + (j << 1);
    const unsigned long long* Wr = sfgw[row];
    int wq = c >> 6, b = c & 63;
    bool f = (Wr[wq] >> b) & 1;
    if (!f) {
      anybg = true; bh0r = min(bh0r, row); bh1r = max(bh1r, row);
      continue;
    }
    if (c > 0 && ((Wr[(c - 1) >> 6] >> ((c - 1) & 63)) & 1)) continue;
    // run start: length = trailing-ones of row mask from bit c
    unsigned long long inv = ~(Wr[wq] >> b);
    int len = inv ? (__ffsll(inv) - 1) : 64;
    if (len == 64 - b) {
      for (int w2 = wq + 1; w2 < 4; w2++) {
        unsigned long long iv2 = ~Wr[w2];
        int t = iv2 ? (__ffsll(iv2) - 1) : 64;
        len += t;
        if (t < 64) break;
      }
    }
    int root = find_halve(slab, (row << 8) + c);
    int id = cid(rm, wpre, root);
    atomicAdd(&sA[id], len);
    atomicMin(&sW0[id], c);
    atomicMax(&sW1[id], c + len - 1);
    atomicMin(&sH0[id], row);
    atomicMax(&sH1[id], row);
  }
  int bw0r = anybg ? c : WW, bw1r = anybg ? c : -1;
  if (!anybg) { bh0r = TRR; bh1r = -1; }
  __syncthreads();

  // P6: emit compact root records + boundary maps (1 boundary px/thread).
  for (int j = 0; j < 8; j++) {
    int p = tid + (j << 9);
    if (slab[p] == p) {
      int id = cid(rm, wpre, p);
      int gid = (lm << 14) + (tile << 10) + id;
      gp[gid] = gid;
      ga[gid] = sA[id];
      gl[gid] = (unsigned short)((tile << 12) + p);
      gbb[gid] = ((unsigned)(R0 + sH0[id]) << 24) | ((unsigned)sW0[id] << 16)
               | ((unsigned)(R0 + sH1[id]) << 8) | (unsigned)sW1[id];
    }
  }
  {
    int brow = (rb == 0) ? 0 : (TRR - 1);
    const unsigned long long* Wr = sfgw[brow];
    unsigned short val = 0xFFFF;
    if ((Wr[c >> 6] >> (c & 63)) & 1) {
      int b = c & 63, w = c >> 6;
      unsigned long long z = ~Wr[w] & (b ? ((1ull << b) - 1) : 0ull);
      int w2 = w;
      while (z == 0 && w2 > 0) { w2--; z = ~Wr[w2]; }
      int start = z ? ((w2 << 6) + 63 - (int)__clzll(z) + 1) : 0;
      int root = find_halve(slab, (brow << 8) + start);
      val = (unsigned short)((tile << 10) + cid(rm, wpre, root));
    }
    gbrow[(q << 9) + ((rb == 0) ? 0 : 256) + c] = val;
  }
  if (tid == 0) gnr[q] = snr;

  // bg bbox + dsum block reductions.
  for (int off = 32; off > 0; off >>= 1) {
    bw0r = min(bw0r, __shfl_down(bw0r, off));
    bw1r = max(bw1r, __shfl_down(bw1r, off));
    bh0r = min(bh0r, __shfl_down(bh0r, off));
    bh1r = max(bh1r, __shfl_down(bh1r, off));
  }
  if (lane == 0) { sbb[0][wv] = bw0r; sbb[1][wv] = bw1r;
                   sbb[2][wv] = bh0r; sbb[3][wv] = bh1r; }
  for (int off = 32; off > 0; off >>= 1) dsum += __shfl_down(dsum, off);
  if (lane == 0) sred[wv] = dsum;
  __syncthreads();
  if (tid == 0) {
    int a0 = sbb[0][0], a1 = sbb[1][0], a2 = sbb[2][0], a3 = sbb[3][0];
    for (int i = 1; i < 8; i++) {
      a0 = min(a0, sbb[0][i]); a1 = max(a1, sbb[1][i]);
      a2 = min(a2, sbb[2][i]); a3 = max(a3, sbb[3][i]);
    }
    if (a1 >= 0) {
      atomicMin(&mt->bw0[gm], a0); atomicMax(&mt->bw1[gm], a1);
      atomicMin(&mt->bh0[gm], R0 + a2); atomicMax(&mt->bh1[gm], R0 + a3);
    }
    double t = 0.0;
    for (int i = 0; i < 8; i++) t += sred[i];
    atomicAdd(&mt->dsum[gm], t);
    if (tile == 0) mt->fg0[gm] = (int)(sfgw[0][0] & 1ull);
  }
}

// One block per mask: seam unions -> area push -> exact top-2 -> bbox sweep.
__global__ __launch_bounds__(1024)
void k_mask(int* __restrict__ gp, int* __restrict__ ga,
            const unsigned int* __restrict__ gbb,
            const unsigned short* __restrict__ gl,
            const unsigned short* __restrict__ gbrow,
            const int* __restrict__ gnr, Meta* __restrict__ mt, int c0) {
  int lm = blockIdx.x, gm = c0 + lm;
  int tid = threadIdx.x;
  int tb = lm << 4;
  int sbase = lm << 14;

  // Phase A: seam unions on compact ids (15 seams x 256 cols).
  for (int idx = tid; idx < 15 * 256; idx += 1024) {
    int s = idx >> 8, c = idx & 255;
    const unsigned short* up = gbrow + ((tb + s) << 9) + 256;
    const unsigned short* lo = gbrow + ((tb + s + 1) << 9);
    unsigned short v16 = lo[c];
    if (v16 == 0xFFFF) continue;
    int v = sbase + v16;
    bool wfg = (c > 0) && (lo[c - 1] != 0xFFFF);
    unsigned short n16 = up[c];
    if (!wfg) {
      if (n16 != 0xFFFF) unite(gp, v, sbase + n16);
      else if (c > 0 && up[c - 1] != 0xFFFF) unite(gp, v, sbase + up[c - 1]);
    }
    if (n16 == 0xFFFF && c < 255 && up[c + 1] != 0xFFFF)
      unite(gp, v, sbase + up[c + 1]);
  }
  __syncthreads();

  // Phase B: push areas of non-final roots into final roots (pushes only
  // target final roots, so no read/write hazard on ga).
  for (int s = tid; s < SPM; s += 1024) {
    if ((s & (SPT - 1)) >= gnr[tb + (s >> 10)]) continue;
    int i = sbase + s;
    int r = find_c(gp, i);
    if (r != i) atomicAdd(&ga[r], ga[i]);
  }
  __syncthreads();

  // Phase C: top-2 with exact lax.top_k candidate set.
  // key = (area<<37)|((SS-lab)<<20)|slot : (area desc, label asc).
  unsigned long long t1 = 0, t2 = 0;
  int fsum = 0;
  for (int s = tid; s < SPM; s += 1024) {
    if ((s & (SPT - 1)) >= gnr[tb + (s >> 10)]) continue;
    int gid = sbase + s;
    if (gp[gid] == gid) {
      int a = ga[gid];
      int lab = gl[gid];
      fsum += a;
      unsigned long long key = ((unsigned long long)a << 37)
                             | ((unsigned long long)(SS - lab) << 20)
                             | (unsigned)s;
      if (key > t1) { t2 = t1; t1 = key; }
      else if (key > t2) t2 = key;
    }
  }
  for (int off = 32; off > 0; off >>= 1) {
    unsigned long long o1 = __shfl_down(t1, off), o2 = __shfl_down(t2, off);
    if (o1 > t1) { t2 = (t1 > o2) ? t1 : o2; t1 = o1; }
    else if (o1 > t2) t2 = o1;
    fsum += __shfl_down(fsum, off);
  }
  __shared__ unsigned long long s1[16], s2[16];
  __shared__ int sf[16];
  __shared__ int ssel, sslot;
  int wv = tid >> 6, lane = tid & 63;
  if (lane == 0) { s1[wv] = t1; s2[wv] = t2; sf[wv] = fsum; }
  __syncthreads();
  if (tid == 0) {
    t1 = s1[0]; t2 = s2[0]; fsum = sf[0];
    for (int i = 1; i < 16; i++) {
      unsigned long long o1 = s1[i], o2 = s2[i];
      if (o1 > t1) { t2 = (t1 > o2) ? t1 : o2; t1 = o1; }
      else if (o1 > t2) t2 = o1;
      fsum += sf[i];
    }
    unsigned long long bg = ((unsigned long long)(SS - fsum)) << 37;
    int zl = mt->fg0[gm] ? 1 : 0;   // best zero-area label (see R7 proof)
    unsigned long long zk = ((unsigned long long)(SS - zl)) << 20;
    if (bg > t1) { t2 = t1; t1 = bg; } else if (bg > t2) t2 = bg;
    if (zk > t1) { t2 = t1; t1 = zk; } else if (zk > t2) t2 = zk;
    if (t2 == bg) {
      ssel = 1;
      mt->h0[gm] = mt->bh0[gm]; mt->h1[gm] = mt->bh1[gm];
      mt->w0[gm] = mt->bw0[gm]; mt->w1[gm] = mt->bw1[gm];
    } else if (t2 == zk) {
      ssel = 2;
      mt->h0[gm] = 1; mt->h1[gm] = 0; mt->w0[gm] = 1; mt->w1[gm] = 0;
    } else {
      ssel = 0; sslot = (int)(t2 & 0xFFFFF);
    }
  }
  __syncthreads();

  // Phase D: union the packed bboxes of all slots in the chosen component.
  if (ssel == 0) {
    int secgid = sbase + sslot;
    int h0l = HH, h1l = -1, w0l = WW, w1l = -1;
    for (int s = tid; s < SPM; s += 1024) {
      if ((s & (SPT - 1)) >= gnr[tb + (s >> 10)]) continue;
      int i = sbase + s;
      if (find_c(gp, i) == secgid) {
        unsigned int bb = gbb[i];
        h0l = min(h0l, (int)(bb >> 24));
        w0l = min(w0l, (int)((bb >> 16) & 255));
        h1l = max(h1l, (int)((bb >> 8) & 255));
        w1l = max(w1l, (int)(bb & 255));
      }
    }
    for (int off = 32; off > 0; off >>= 1) {
      h0l = min(h0l, __shfl_down(h0l, off));
      w0l = min(w0l, __shfl_down(w0l, off));
      h1l = max(h1l, __shfl_down(h1l, off));
      w1l = max(w1l, __shfl_down(w1l, off));
    }
    __shared__ int r0[16], r1[16], r2[16], r3[16];
    if (lane == 0) { r0[wv] = h0l; r1[wv] = h1l; r2[wv] = w0l; r3[wv] = w1l; }
    __syncthreads();
    if (tid == 0) {
      for (int i = 1; i < 16; i++) {
        r0[0] = min(r0[0], r0[i]); r1[0] = max(r1[0], r1[i]);
        r2[0] = min(r2[0], r2[i]); r3[0] = max(r3[0], r3[i]);
      }
      mt->h0[gm] = r0[0]; mt->h1[gm] = r1[0];
      mt->w0[gm] = r2[0]; mt->w1[gm] = r3[0];
    }
  }
}

// 8 blocks per mask over the bbox rows; double partials into dins.
__global__ void k_inside(const float* __restrict__ in, Meta* __restrict__ mt,
                         int c0) {
  int b = blockIdx.x;
  int lm = b >> 3, seg = b & 7;
  int gm = c0 + lm;
  int h0 = mt->h0[gm], h1 = mt->h1[gm], w0 = mt->w0[gm], w1 = mt->w1[gm];
  double acc = 0.0;
  if (h1 >= h0) {
    int cc = w0 + threadIdx.x;
    if (cc <= w1) {
      const float* base = in + ((size_t)gm << 16);
      for (int rr = h0 + seg; rr <= h1; rr += 8) {
        float x = base[(rr << 8) + cc];
        acc += (double)fmaxf((x + 1.0f) * 0.5f, 0.0f);
      }
    }
  }
  for (int off = 32; off > 0; off >>= 1) acc += __shfl_down(acc, off);
  __shared__ double sd[4];
  int wid = threadIdx.x >> 6, lane = threadIdx.x & 63;
  if (lane == 0) sd[wid] = acc;
  __syncthreads();
  if (threadIdx.x == 0) {
    double t = sd[0] + sd[1] + sd[2] + sd[3];
    if (t != 0.0) atomicAdd(&mt->dins[gm], t);
  }
}

__global__ void k_final(const Meta* __restrict__ mt, float* __restrict__ out) {
  __shared__ double sd[NM];
  int t = threadIdx.x;
  sd[t] = (mt->dsum[t] - mt->dins[t]) / (double)SS;
  __syncthreads();
  for (int off = 64; off > 0; off >>= 1) {
    if (t < off) sd[t] += sd[t + off];
    __syncthreads();
  }
  if (t == 0) out[0] = (float)(sd[0] / (double)NM);
}

extern "C" void kernel_launch(void* const* d_in, const int* in_sizes, int n_in,
                              void* d_out, int out_size, void* d_ws,
                              size_t ws_size, hipStream_t stream) {
  const float* in = (const float*)d_in[0];
  float* out = (float*)d_out;

  Meta* mt = (Meta*)d_ws;
  const size_t meta_bytes = (sizeof(Meta) + 255) & ~(size_t)255;
  char* base = (char*)d_ws + meta_bytes;
  size_t avail = (ws_size > meta_bytes) ? (ws_size - meta_bytes) : 0;
  // per-mask bytes: gp,ga,gbb (4B x 16384 each) + gl (2B x 16384) +
  // gbrow (2B x 16 x 512) + gnr (4B x 16) = 245,824 -> chunk = 128 at 32 MiB.
  const size_t per_mask =
      (size_t)SPM * (4 + 4 + 4 + 2) + (size_t)NT2 * 512 * 2 + NT2 * 4;
  int chunk = (int)(avail / per_mask);
  if (chunk > NM) chunk = NM;
  if (chunk < 1) return;  // insufficient workspace (would fail validation)

  char* ptr = base;
  int* gp = (int*)ptr;                 ptr += (size_t)chunk * SPM * 4;
  int* ga = (int*)ptr;                 ptr += (size_t)chunk * SPM * 4;
  unsigned int* gbb = (unsigned int*)ptr;       ptr += (size_t)chunk * SPM * 4;
  unsigned short* gl = (unsigned short*)ptr;    ptr += (size_t)chunk * SPM * 2;
  unsigned short* gbrow = (unsigned short*)ptr; ptr += (size_t)chunk * NT2 * 512 * 2;
  int* gnr = (int*)ptr;

  k_meta_init<<<1, 128, 0, stream>>>(mt);
  for (int c0 = 0; c0 < NM; c0 += chunk) {
    int cn = (chunk < NM - c0) ? chunk : (NM - c0);
    k_local<<<cn * NT2, 512, 0, stream>>>(in, c0, gp, ga, gbb, gl, gbrow,
                                          gnr, mt);
    k_mask <<<cn, 1024, 0, stream>>>(gp, ga, gbb, gl, gbrow, gnr, mt, c0);
    k_inside<<<cn * 8, 256, 0, stream>>>(in, mt, c0);
  }
  k_final<<<1, 128, 0, stream>>>(mt, out);
}

// Round 9
// 246.187 us; speedup vs baseline: 1.1465x; 1.0596x over previous
//
#include <hip/hip_runtime.h>

#define HH 256
#define WW 256
#define SS 65536   // pixels per mask; also the background sentinel label
#define NM 128     // B*K masks
#define TRR 16     // rows per tile
#define NT2 16     // tiles per mask
#define RMX 2048   // max horizontal runs in a 16x256 tile
#define SPT 1024   // max 8-conn components in a 16x256 tile
#define SPM 16384  // slots per mask (16 tiles x 1024)

struct Meta {
  double dsum[NM];   // total sum of m per mask
  double dins[NM];   // sum of m inside suppressed bbox
  int bh0[NM]; int bh1[NM]; int bw0[NM]; int bw1[NM];  // background bbox
  int fg0[NM];       // is mask pixel 0 foreground
};

__global__ void k_meta_init(Meta* mt) {
  int i = threadIdx.x;
  if (i < NM) {
    mt->dsum[i] = 0.0; mt->dins[i] = 0.0; mt->fg0[i] = 0;
    mt->bh0[i] = HH; mt->bh1[i] = -1; mt->bw0[i] = WW; mt->bw1[i] = -1;
  }
}

// Find with plain-store path compression (ECL-CC). Safe concurrent with
// atomicMin linking: stored values are live ancestors; parent < child.
__device__ __forceinline__ int find_c(int* L, int x) {
  int p = L[x];
  if (p == x) return x;
  int root = p, q = L[root];
  while (q != root) { root = q; q = L[root]; }
  if (root != p) L[x] = root;
  return root;
}

// Link larger root -> smaller root: final root = min id. Run/compact ids are
// assigned in pixel order of run starts, so min id == the reference's
// min-pixel-index component label.
__device__ void unite(int* L, int a, int b) {
  bool done = false;
  do {
    a = find_c(L, a);
    b = find_c(L, b);
    if (a < b)      { int old = atomicMin(&L[b], a); done = (old == b); b = old; }
    else if (b < a) { int old = atomicMin(&L[a], b); done = (old == a); a = old; }
    else done = true;
  } while (!done);
}

// Path-halving find (static tree; races only lose compression).
__device__ __forceinline__ int find_halve(int* L, int x) {
  int p = L[x];
  while (p != x) {
    int gp = L[p];
    if (gp == p) return p;
    L[x] = gp;
    x = p; p = gp;
  }
  return x;
}

__device__ __forceinline__ int cid(const unsigned long long* rm,
                                   const int* rpre, int r) {
  int w = r >> 6, b = r & 63;
  return rpre[w] + (int)__popcll(rm[w] & (b ? ((1ull << b) - 1) : 0ull));
}

__device__ __forceinline__ unsigned long long mask_le(int b) {  // bits 0..b
  return (b == 63) ? ~0ull : ((1ull << (b + 1)) - 1);
}
__device__ __forceinline__ unsigned long long mask_lt(int b) {  // bits 0..b-1
  return b ? ((1ull << b) - 1) : 0ull;
}

// One block = one 16x256 tile. RUN-based union-find: nodes are horizontal
// runs (<=2048), enumerated from row bitmasks; per-pixel slab eliminated.
__global__ __launch_bounds__(512)
void k_local(const float* __restrict__ in, int cb,
             int* __restrict__ gp, int* __restrict__ ga,
             unsigned int* __restrict__ gbb, unsigned short* __restrict__ gl,
             unsigned short* __restrict__ gbrow, int* __restrict__ gnr,
             Meta* __restrict__ mt) {
  __shared__ unsigned long long sfgw[TRR][4];   // fg row bitmasks
  __shared__ unsigned char sfgc[TRR][32];
  __shared__ unsigned long long srs[TRR][4];    // run-start bitmasks
  __shared__ int wpre64[64];   // global run-id base per (row,word)
  __shared__ int snr;          // total runs
  __shared__ int sspan[RMX];   // (row<<16)|(a<<8)|b
  __shared__ int suf[RMX];     // UF parent over run ids
  __shared__ unsigned long long rootm[32];      // root bitmask over run ids
  __shared__ int rpre[32];
  __shared__ int sA[SPT], sW0[SPT], sW1[SPT], sH0[SPT], sH1[SPT];  // 20 KB
  __shared__ double sred[8];
  __shared__ int sbb[4][8];

  int q = blockIdx.x, lm = q >> 4, tile = q & 15;
  int tid = threadIdx.x, lane = tid & 63, wv = tid >> 6;
  int gm = cb + lm, R0 = tile << 4;

  // P1: load input (8 contiguous px/thread), m, dsum, fg bits — identical
  // order to prior rounds -> bit-identical dsum.
  int r1 = tid >> 5, cs = tid & 31;
  const float4* src =
      (const float4*)(in + ((size_t)gm << 16) + ((R0 + r1) << 8) + (cs << 3));
  double dsum = 0.0;
  unsigned int fgb = 0;
  for (int k = 0; k < 2; k++) {
    float4 v = src[k];
    float m0 = fmaxf((v.x + 1.0f) * 0.5f, 0.0f);
    float m1 = fmaxf((v.y + 1.0f) * 0.5f, 0.0f);
    float m2 = fmaxf((v.z + 1.0f) * 0.5f, 0.0f);
    float m3 = fmaxf((v.w + 1.0f) * 0.5f, 0.0f);
    dsum += (double)m0 + (double)m1 + (double)m2 + (double)m3;
    fgb |= ((m0 > 0.5f) ? 1u : 0u) << (4 * k);
    fgb |= ((m1 > 0.5f) ? 1u : 0u) << (4 * k + 1);
    fgb |= ((m2 > 0.5f) ? 1u : 0u) << (4 * k + 2);
    fgb |= ((m3 > 0.5f) ? 1u : 0u) << (4 * k + 3);
  }
  sfgc[r1][cs] = (unsigned char)fgb;
  __syncthreads();
  if (tid < 64) {   // 16 rows x 4 words
    int row = tid >> 2, w = tid & 3;
    const unsigned char* pc = &sfgc[row][w << 3];
    unsigned long long wd = 0;
    for (int i = 0; i < 8; i++) wd |= ((unsigned long long)pc[i]) << (i << 3);
    sfgw[row][w] = wd;
  }
  __syncthreads();

  // P2 (wave 0): run-start masks, global run ids via wave prefix, span
  // enumeration. Other waves zero the per-component stats arrays.
  if (tid < 64) {
    int row = tid >> 2, w = tid & 3;
    unsigned long long W = sfgw[row][w];
    unsigned long long carry = (w > 0) ? (sfgw[row][w - 1] >> 63) : 0ull;
    unsigned long long rs = W & ~((W << 1) | carry);
    srs[row][w] = rs;
    int cnt = (int)__popcll(rs);
    int sa = cnt;
    for (int off = 1; off < 64; off <<= 1) {
      int t = __shfl_up(sa, off);
      if (tid >= off) sa += t;
    }
    wpre64[tid] = sa - cnt;
    if (tid == 63) snr = sa;
    // serial span emission for this (row, word)
    int id = sa - cnt;
    unsigned long long bits = rs;
    while (bits) {
      int a = (int)__ffsll(bits) - 1;
      bits &= bits - 1;
      int A = (w << 6) + a;
      unsigned long long inv = ~(W >> a);
      int len = inv ? ((int)__ffsll(inv) - 1) : (64 - a);
      if (len == 64 - a) {
        for (int w2 = w + 1; w2 < 4; w2++) {
          unsigned long long iv2 = ~sfgw[row][w2];
          int t = iv2 ? ((int)__ffsll(iv2) - 1) : 64;
          len += t;
          if (t < 64) break;
        }
      }
      sspan[id] = (row << 16) | (A << 8) | (A + len - 1);
      suf[id] = id;
      id++;
    }
  } else {
    for (int s = tid - 64; s < SPT; s += 448) {
      sA[s] = 0; sW0[s] = WW; sW1[s] = -1; sH0[s] = TRR; sH1[s] = -1;
    }
  }
  __syncthreads();

  int nr = snr;

  // P3: run-to-run unions via windowed overlap with the previous row.
  for (int i = tid; i < nr; i += 512) {
    int sp = sspan[i];
    int row = sp >> 16, a = (sp >> 8) & 255, b = sp & 255;
    if (row == 0) continue;
    int lo = max(a - 1, 0), hi = min(b + 1, 255);
    const unsigned long long* Wp = sfgw[row - 1];
    const unsigned long long* Rp = srs[row - 1];
    int prebase = (row - 1) << 2;
    // straddling run: covers lo but starts before it
    int lw = lo >> 6, lb = lo & 63;
    if (((Wp[lw] >> lb) & 1) && !((Rp[lw] >> lb) & 1)) {
      int j = wpre64[prebase + lw] + (int)__popcll(Rp[lw] & mask_le(lb)) - 1;
      unite(suf, i, j);
    }
    // runs starting inside [lo, hi]
    for (int w = lw; w <= (hi >> 6); w++) {
      unsigned long long m = Rp[w];
      if (w == lw) m &= ~mask_lt(lb);
      if (w == (hi >> 6)) m &= mask_le(hi & 63);
      int base2 = wpre64[prebase + w];
      while (m) {
        int bb = (int)__ffsll(m) - 1;
        m &= m - 1;
        int j = base2 + (int)__popcll(Rp[w] & mask_lt(bb));
        unite(suf, i, j);
      }
    }
  }
  __syncthreads();

  // P4: root bitmask over run ids (parent==self ballot), compact prefix.
  for (int j = 0; j < 4; j++) {
    int i = tid + (j << 9);
    unsigned long long bal = __ballot(i < nr && suf[i] == i);
    if (lane == 0) rootm[wv + (j << 3)] = bal;
  }
  __syncthreads();
  if (tid < 32) {
    int pc = (int)__popcll(rootm[tid]);
    int sa = pc;
    for (int off = 1; off < 32; off <<= 1) {
      int t = __shfl_up(sa, off);
      if (tid >= off) sa += t;
    }
    rpre[tid] = sa - pc;
  }
  __syncthreads();

  // P5: per-run stats into per-component accumulators.
  for (int i = tid; i < nr; i += 512) {
    int root = find_halve(suf, i);
    int id = cid(rootm, rpre, root);
    int sp = sspan[i];
    int row = sp >> 16, a = (sp >> 8) & 255, b = sp & 255;
    atomicAdd(&sA[id], b - a + 1);
    atomicMin(&sW0[id], a);
    atomicMax(&sW1[id], b);
    atomicMin(&sH0[id], row);
    atomicMax(&sH1[id], row);
  }
  __syncthreads();

  // P6a: emit compact root records.
  int nc = rpre[31] + (int)__popcll(rootm[31]);
  for (int i = tid; i < nr; i += 512) {
    if (suf[i] == i) {
      int id = cid(rootm, rpre, i);
      int gid = (lm << 14) + (tile << 10) + id;
      int sp = sspan[i];
      gp[gid] = gid;
      ga[gid] = sA[id];
      gl[gid] = (unsigned short)((tile << 12) + ((sp >> 16) << 8) +
                                 ((sp >> 8) & 255));
      gbb[gid] = ((unsigned)(R0 + sH0[id]) << 24) | ((unsigned)sW0[id] << 16)
               | ((unsigned)(R0 + sH1[id]) << 8) | (unsigned)sW1[id];
    }
  }
  // P6b: boundary maps (1 boundary px/thread: 2 rows x 256 cols).
  {
    int c = tid & 255, topbot = tid >> 8;
    int brow = topbot ? (TRR - 1) : 0;
    unsigned short val = 0xFFFF;
    if ((sfgw[brow][c >> 6] >> (c & 63)) & 1) {
      int w = c >> 6, bb = c & 63;
      int id = wpre64[(brow << 2) + w] +
               (int)__popcll(srs[brow][w] & mask_le(bb)) - 1;
      int root = find_halve(suf, id);
      val = (unsigned short)((tile << 10) + cid(rootm, rpre, root));
    }
    gbrow[(q << 9) + (topbot ? 256 : 0) + c] = val;
  }
  if (tid == 0) gnr[q] = nc;

  // P7: bg bbox (thread = column c, half the rows) + dsum reductions.
  int c = tid & 255, half = (tid >> 8) << 3;
  int bh0r = TRR, bh1r = -1;
  bool anybg = false;
  for (int row = half; row < half + 8; row++) {
    if (!((sfgw[row][c >> 6] >> (c & 63)) & 1)) {
      anybg = true;
      bh0r = min(bh0r, row); bh1r = max(bh1r, row);
    }
  }
  int bw0r = anybg ? c : WW, bw1r = anybg ? c : -1;
  for (int off = 32; off > 0; off >>= 1) {
    bw0r = min(bw0r, __shfl_down(bw0r, off));
    bw1r = max(bw1r, __shfl_down(bw1r, off));
    bh0r = min(bh0r, __shfl_down(bh0r, off));
    bh1r = max(bh1r, __shfl_down(bh1r, off));
  }
  if (lane == 0) { sbb[0][wv] = bw0r; sbb[1][wv] = bw1r;
                   sbb[2][wv] = bh0r; sbb[3][wv] = bh1r; }
  for (int off = 32; off > 0; off >>= 1) dsum += __shfl_down(dsum, off);
  if (lane == 0) sred[wv] = dsum;
  __syncthreads();
  if (tid == 0) {
    int a0 = sbb[0][0], a1 = sbb[1][0], a2 = sbb[2][0], a3 = sbb[3][0];
    for (int i = 1; i < 8; i++) {
      a0 = min(a0, sbb[0][i]); a1 = max(a1, sbb[1][i]);
      a2 = min(a2, sbb[2][i]); a3 = max(a3, sbb[3][i]);
    }
    if (a1 >= 0) {
      atomicMin(&mt->bw0[gm], a0); atomicMax(&mt->bw1[gm], a1);
      atomicMin(&mt->bh0[gm], R0 + a2); atomicMax(&mt->bh1[gm], R0 + a3);
    }
    double t = 0.0;
    for (int i = 0; i < 8; i++) t += sred[i];
    atomicAdd(&mt->dsum[gm], t);
    if (tile == 0) mt->fg0[gm] = (int)(sfgw[0][0] & 1ull);
  }
}

// One block per mask: seam unions -> area push -> exact top-2 -> bbox sweep
// -> fused inside-bbox sum (writes dins; no extra kernel).
__global__ __launch_bounds__(1024)
void k_mask(const float* __restrict__ in, int* __restrict__ gp,
            int* __restrict__ ga, const unsigned int* __restrict__ gbb,
            const unsigned short* __restrict__ gl,
            const unsigned short* __restrict__ gbrow,
            const int* __restrict__ gnr, Meta* __restrict__ mt, int c0) {
  int lm = blockIdx.x, gm = c0 + lm;
  int tid = threadIdx.x;
  int tb = lm << 4;
  int sbase = lm << 14;
  __shared__ int sh0, sh1, sw0, sw1;

  // Phase A: seam unions on compact ids (15 seams x 256 cols).
  for (int idx = tid; idx < 15 * 256; idx += 1024) {
    int s = idx >> 8, c = idx & 255;
    const unsigned short* up = gbrow + ((tb + s) << 9) + 256;
    const unsigned short* lo = gbrow + ((tb + s + 1) << 9);
    unsigned short v16 = lo[c];
    if (v16 == 0xFFFF) continue;
    int v = sbase + v16;
    bool wfg = (c > 0) && (lo[c - 1] != 0xFFFF);
    unsigned short n16 = up[c];
    if (!wfg) {
      if (n16 != 0xFFFF) unite(gp, v, sbase + n16);
      else if (c > 0 && up[c - 1] != 0xFFFF) unite(gp, v, sbase + up[c - 1]);
    }
    if (n16 == 0xFFFF && c < 255 && up[c + 1] != 0xFFFF)
      unite(gp, v, sbase + up[c + 1]);
  }
  __syncthreads();

  // Phase B: push areas of non-final roots into final roots.
  for (int s = tid; s < SPM; s += 1024) {
    if ((s & (SPT - 1)) >= gnr[tb + (s >> 10)]) continue;
    int i = sbase + s;
    int r = find_c(gp, i);
    if (r != i) atomicAdd(&ga[r], ga[i]);
  }
  __syncthreads();

  // Phase C: top-2 with exact lax.top_k candidate set.
  // key = (area<<37)|((SS-lab)<<20)|slot : (area desc, label asc).
  unsigned long long t1 = 0, t2 = 0;
  int fsum = 0;
  for (int s = tid; s < SPM; s += 1024) {
    if ((s & (SPT - 1)) >= gnr[tb + (s >> 10)]) continue;
    int gid = sbase + s;
    if (gp[gid] == gid) {
      int a = ga[gid];
      int lab = gl[gid];
      fsum += a;
      unsigned long long key = ((unsigned long long)a << 37)
                             | ((unsigned long long)(SS - lab) << 20)
                             | (unsigned)s;
      if (key > t1) { t2 = t1; t1 = key; }
      else if (key > t2) t2 = key;
    }
  }
  for (int off = 32; off > 0; off >>= 1) {
    unsigned long long o1 = __shfl_down(t1, off), o2 = __shfl_down(t2, off);
    if (o1 > t1) { t2 = (t1 > o2) ? t1 : o2; t1 = o1; }
    else if (o1 > t2) t2 = o1;
    fsum += __shfl_down(fsum, off);
  }
  __shared__ unsigned long long s1[16], s2[16];
  __shared__ int sf[16];
  __shared__ int ssel, sslot;
  int wv = tid >> 6, lane = tid & 63;
  if (lane == 0) { s1[wv] = t1; s2[wv] = t2; sf[wv] = fsum; }
  __syncthreads();
  if (tid == 0) {
    t1 = s1[0]; t2 = s2[0]; fsum = sf[0];
    for (int i = 1; i < 16; i++) {
      unsigned long long o1 = s1[i], o2 = s2[i];
      if (o1 > t1) { t2 = (t1 > o2) ? t1 : o2; t1 = o1; }
      else if (o1 > t2) t2 = o1;
      fsum += sf[i];
    }
    unsigned long long bg = ((unsigned long long)(SS - fsum)) << 37;
    int zl = mt->fg0[gm] ? 1 : 0;   // best zero-area label (R5/R7 proof)
    unsigned long long zk = ((unsigned long long)(SS - zl)) << 20;
    if (bg > t1) { t2 = t1; t1 = bg; } else if (bg > t2) t2 = bg;
    if (zk > t1) { t2 = t1; t1 = zk; } else if (zk > t2) t2 = zk;
    if (t2 == bg) {
      ssel = 1;
      sh0 = mt->bh0[gm]; sh1 = mt->bh1[gm];
      sw0 = mt->bw0[gm]; sw1 = mt->bw1[gm];
    } else if (t2 == zk) {
      ssel = 2;
      sh0 = 1; sh1 = 0; sw0 = 1; sw1 = 0;   // empty bbox
    } else {
      ssel = 0; sslot = (int)(t2 & 0xFFFFF);
    }
  }
  __syncthreads();

  // Phase D: union the packed bboxes of all slots in the chosen component.
  if (ssel == 0) {
    int secgid = sbase + sslot;
    int h0l = HH, h1l = -1, w0l = WW, w1l = -1;
    for (int s = tid; s < SPM; s += 1024) {
      if ((s & (SPT - 1)) >= gnr[tb + (s >> 10)]) continue;
      int i = sbase + s;
      if (find_c(gp, i) == secgid) {
        unsigned int bb = gbb[i];
        h0l = min(h0l, (int)(bb >> 24));
        w0l = min(w0l, (int)((bb >> 16) & 255));
        h1l = max(h1l, (int)((bb >> 8) & 255));
        w1l = max(w1l, (int)(bb & 255));
      }
    }
    for (int off = 32; off > 0; off >>= 1) {
      h0l = min(h0l, __shfl_down(h0l, off));
      w0l = min(w0l, __shfl_down(w0l, off));
      h1l = max(h1l, __shfl_down(h1l, off));
      w1l = max(w1l, __shfl_down(w1l, off));
    }
    __shared__ int r0[16], r1[16], r2[16], r3[16];
    if (lane == 0) { r0[wv] = h0l; r1[wv] = h1l; r2[wv] = w0l; r3[wv] = w1l; }
    __syncthreads();
    if (tid == 0) {
      for (int i = 1; i < 16; i++) {
        r0[0] = min(r0[0], r0[i]); r1[0] = max(r1[0], r1[i]);
        r2[0] = min(r2[0], r2[i]); r3[0] = max(r3[0], r3[i]);
      }
      sh0 = r0[0]; sh1 = r1[0]; sw0 = r2[0]; sw1 = r3[0];
    }
  }
  __syncthreads();

  // Phase E: fused inside-bbox sum (4 row-groups x 256 cols, coalesced).
  double acc = 0.0;
  int h0 = sh0, h1 = sh1, w0 = sw0, w1 = sw1;
  if (h1 >= h0) {
    int cc = w0 + (tid & 255);
    if (cc <= w1) {
      const float* basep = in + ((size_t)gm << 16);
      for (int rr = h0 + (tid >> 8); rr <= h1; rr += 4) {
        acc += (double)fmaxf((basep[(rr << 8) + cc] + 1.0f) * 0.5f, 0.0f);
      }
    }
  }
  for (int off = 32; off > 0; off >>= 1) acc += __shfl_down(acc, off);
  __shared__ double sdd[16];
  if (lane == 0) sdd[wv] = acc;
  __syncthreads();
  if (tid == 0) {
    double t = 0.0;
    for (int i = 0; i < 16; i++) t += sdd[i];
    mt->dins[gm] = t;
  }
}

__global__ void k_final(const Meta* __restrict__ mt, float* __restrict__ out) {
  __shared__ double sd[NM];
  int t = threadIdx.x;
  sd[t] = (mt->dsum[t] - mt->dins[t]) / (double)SS;
  __syncthreads();
  for (int off = 64; off > 0; off >>= 1) {
    if (t < off) sd[t] += sd[t + off];
    __syncthreads();
  }
  if (t == 0) out[0] = (float)(sd[0] / (double)NM);
}

extern "C" void kernel_launch(void* const* d_in, const int* in_sizes, int n_in,
                              void* d_out, int out_size, void* d_ws,
                              size_t ws_size, hipStream_t stream) {
  const float* in = (const float*)d_in[0];
  float* out = (float*)d_out;

  Meta* mt = (Meta*)d_ws;
  const size_t meta_bytes = (sizeof(Meta) + 255) & ~(size_t)255;
  char* base = (char*)d_ws + meta_bytes;
  size_t avail = (ws_size > meta_bytes) ? (ws_size - meta_bytes) : 0;
  const size_t per_mask =
      (size_t)SPM * (4 + 4 + 4 + 2) + (size_t)NT2 * 512 * 2 + NT2 * 4;
  int chunk = (int)(avail / per_mask);
  if (chunk > NM) chunk = NM;
  if (chunk < 1) return;  // insufficient workspace (would fail validation)

  char* ptr = base;
  int* gp = (int*)ptr;                 ptr += (size_t)chunk * SPM * 4;
  int* ga = (int*)ptr;                 ptr += (size_t)chunk * SPM * 4;
  unsigned int* gbb = (unsigned int*)ptr;       ptr += (size_t)chunk * SPM * 4;
  unsigned short* gl = (unsigned short*)ptr;    ptr += (size_t)chunk * SPM * 2;
  unsigned short* gbrow = (unsigned short*)ptr; ptr += (size_t)chunk * NT2 * 512 * 2;
  int* gnr = (int*)ptr;

  k_meta_init<<<1, 128, 0, stream>>>(mt);
  for (int c0 = 0; c0 < NM; c0 += chunk) {
    int cn = (chunk < NM - c0) ? chunk : (NM - c0);
    k_local<<<cn * NT2, 512, 0, stream>>>(in, c0, gp, ga, gbb, gl, gbrow,
                                          gnr, mt);
    k_mask <<<cn, 1024, 0, stream>>>(in, gp, ga, gbb, gl, gbrow, gnr, mt, c0);
  }
  k_final<<<1, 128, 0, stream>>>(mt, out);
}

// Round 10
// 210.625 us; speedup vs baseline: 1.3400x; 1.1688x over previous
//
#include <hip/hip_runtime.h>

#define HH 256
#define WW 256
#define SS 65536   // pixels per mask; also the background sentinel label
#define NM 128     // B*K masks
#define TRR 16     // rows per tile
#define NT2 16     // tiles per mask
#define RMX 2048   // max horizontal runs in a 16x256 tile
#define SPT 1024   // max 8-conn components in a 16x256 tile
#define SPM 16384  // slots per mask (16 tiles x 1024)

struct Meta {
  double dsum[NM];   // total sum of m per mask
  double dins[NM];   // sum of m inside suppressed bbox
  int h0[NM]; int h1[NM]; int w0[NM]; int w1[NM];      // chosen bbox, inclusive
  int bh0[NM]; int bh1[NM]; int bw0[NM]; int bw1[NM];  // background bbox
  int fg0[NM];       // is mask pixel 0 foreground
};

__global__ void k_meta_init(Meta* mt) {
  int i = threadIdx.x;
  if (i < NM) {
    mt->dsum[i] = 0.0; mt->dins[i] = 0.0; mt->fg0[i] = 0;
    mt->h0[i] = 1; mt->h1[i] = 0; mt->w0[i] = 1; mt->w1[i] = 0;
    mt->bh0[i] = HH; mt->bh1[i] = -1; mt->bw0[i] = WW; mt->bw1[i] = -1;
  }
}

// Find with plain-store path compression (ECL-CC). Safe concurrent with
// atomicMin linking: stored values are live ancestors; parent < child.
__device__ __forceinline__ int find_c(int* L, int x) {
  int p = L[x];
  if (p == x) return x;
  int root = p, q = L[root];
  while (q != root) { root = q; q = L[root]; }
  if (root != p) L[x] = root;
  return root;
}

// Link larger root -> smaller root: final root = min id. Run/compact ids are
// assigned in pixel order of run starts, so min id == the reference's
// min-pixel-index component label.
__device__ void unite(int* L, int a, int b) {
  bool done = false;
  do {
    a = find_c(L, a);
    b = find_c(L, b);
    if (a < b)      { int old = atomicMin(&L[b], a); done = (old == b); b = old; }
    else if (b < a) { int old = atomicMin(&L[a], b); done = (old == a); a = old; }
    else done = true;
  } while (!done);
}

// Path-halving find (static tree; races only lose compression).
__device__ __forceinline__ int find_halve(int* L, int x) {
  int p = L[x];
  while (p != x) {
    int gp = L[p];
    if (gp == p) return p;
    L[x] = gp;
    x = p; p = gp;
  }
  return x;
}

__device__ __forceinline__ int cid(const unsigned long long* rm,
                                   const int* rpre, int r) {
  int w = r >> 6, b = r & 63;
  return rpre[w] + (int)__popcll(rm[w] & (b ? ((1ull << b) - 1) : 0ull));
}

__device__ __forceinline__ unsigned long long mask_le(int b) {  // bits 0..b
  return (b == 63) ? ~0ull : ((1ull << (b + 1)) - 1);
}
__device__ __forceinline__ unsigned long long mask_lt(int b) {  // bits 0..b-1
  return b ? ((1ull << b) - 1) : 0ull;
}

// One block = one 16x256 tile. RUN-based union-find: nodes are horizontal
// runs (<=2048), enumerated from row bitmasks; per-pixel slab eliminated.
__global__ __launch_bounds__(512)
void k_local(const float* __restrict__ in, int cb,
             int* __restrict__ gp, int* __restrict__ ga,
             unsigned int* __restrict__ gbb, unsigned short* __restrict__ gl,
             unsigned short* __restrict__ gbrow, int* __restrict__ gnr,
             Meta* __restrict__ mt) {
  __shared__ unsigned long long sfgw[TRR][4];   // fg row bitmasks
  __shared__ unsigned char sfgc[TRR][32];
  __shared__ unsigned long long srs[TRR][4];    // run-start bitmasks
  __shared__ int wpre64[64];   // global run-id base per (row,word)
  __shared__ int snr;          // total runs
  __shared__ int sspan[RMX];   // (row<<16)|(a<<8)|b
  __shared__ int suf[RMX];     // UF parent over run ids
  __shared__ unsigned long long rootm[32];      // root bitmask over run ids
  __shared__ int rpre[32];
  __shared__ int sA[SPT], sW0[SPT], sW1[SPT], sH0[SPT], sH1[SPT];  // 20 KB
  __shared__ double sred[8];
  __shared__ int sbb[4][8];

  int q = blockIdx.x, lm = q >> 4, tile = q & 15;
  int tid = threadIdx.x, lane = tid & 63, wv = tid >> 6;
  int gm = cb + lm, R0 = tile << 4;

  // P1: load input (8 contiguous px/thread), m, dsum, fg bits — identical
  // order to prior rounds -> bit-identical dsum.
  int r1 = tid >> 5, cs = tid & 31;
  const float4* src =
      (const float4*)(in + ((size_t)gm << 16) + ((R0 + r1) << 8) + (cs << 3));
  double dsum = 0.0;
  unsigned int fgb = 0;
  for (int k = 0; k < 2; k++) {
    float4 v = src[k];
    float m0 = fmaxf((v.x + 1.0f) * 0.5f, 0.0f);
    float m1 = fmaxf((v.y + 1.0f) * 0.5f, 0.0f);
    float m2 = fmaxf((v.z + 1.0f) * 0.5f, 0.0f);
    float m3 = fmaxf((v.w + 1.0f) * 0.5f, 0.0f);
    dsum += (double)m0 + (double)m1 + (double)m2 + (double)m3;
    fgb |= ((m0 > 0.5f) ? 1u : 0u) << (4 * k);
    fgb |= ((m1 > 0.5f) ? 1u : 0u) << (4 * k + 1);
    fgb |= ((m2 > 0.5f) ? 1u : 0u) << (4 * k + 2);
    fgb |= ((m3 > 0.5f) ? 1u : 0u) << (4 * k + 3);
  }
  sfgc[r1][cs] = (unsigned char)fgb;
  __syncthreads();
  if (tid < 64) {   // 16 rows x 4 words
    int row = tid >> 2, w = tid & 3;
    const unsigned char* pc = &sfgc[row][w << 3];
    unsigned long long wd = 0;
    for (int i = 0; i < 8; i++) wd |= ((unsigned long long)pc[i]) << (i << 3);
    sfgw[row][w] = wd;
  }
  __syncthreads();

  // P2 (wave 0): run-start masks, global run ids via wave prefix, span
  // enumeration. Other waves zero the per-component stats arrays.
  if (tid < 64) {
    int row = tid >> 2, w = tid & 3;
    unsigned long long W = sfgw[row][w];
    unsigned long long carry = (w > 0) ? (sfgw[row][w - 1] >> 63) : 0ull;
    unsigned long long rs = W & ~((W << 1) | carry);
    srs[row][w] = rs;
    int cnt = (int)__popcll(rs);
    int sa = cnt;
    for (int off = 1; off < 64; off <<= 1) {
      int t = __shfl_up(sa, off);
      if (tid >= off) sa += t;
    }
    wpre64[tid] = sa - cnt;
    if (tid == 63) snr = sa;
    // serial span emission for this (row, word)
    int id = sa - cnt;
    unsigned long long bits = rs;
    while (bits) {
      int a = (int)__ffsll(bits) - 1;
      bits &= bits - 1;
      int A = (w << 6) + a;
      unsigned long long inv = ~(W >> a);
      int len = inv ? ((int)__ffsll(inv) - 1) : (64 - a);
      if (len == 64 - a) {
        for (int w2 = w + 1; w2 < 4; w2++) {
          unsigned long long iv2 = ~sfgw[row][w2];
          int t = iv2 ? ((int)__ffsll(iv2) - 1) : 64;
          len += t;
          if (t < 64) break;
        }
      }
      sspan[id] = (row << 16) | (A << 8) | (A + len - 1);
      suf[id] = id;
      id++;
    }
  } else {
    for (int s = tid - 64; s < SPT; s += 448) {
      sA[s] = 0; sW0[s] = WW; sW1[s] = -1; sH0[s] = TRR; sH1[s] = -1;
    }
  }
  __syncthreads();

  int nr = snr;

  // P3: run-to-run unions via windowed overlap with the previous row.
  for (int i = tid; i < nr; i += 512) {
    int sp = sspan[i];
    int row = sp >> 16, a = (sp >> 8) & 255, b = sp & 255;
    if (row == 0) continue;
    int lo = max(a - 1, 0), hi = min(b + 1, 255);
    const unsigned long long* Wp = sfgw[row - 1];
    const unsigned long long* Rp = srs[row - 1];
    int prebase = (row - 1) << 2;
    int lw = lo >> 6, lb = lo & 63;
    if (((Wp[lw] >> lb) & 1) && !((Rp[lw] >> lb) & 1)) {
      int j = wpre64[prebase + lw] + (int)__popcll(Rp[lw] & mask_le(lb)) - 1;
      unite(suf, i, j);
    }
    for (int w = lw; w <= (hi >> 6); w++) {
      unsigned long long m = Rp[w];
      if (w == lw) m &= ~mask_lt(lb);
      if (w == (hi >> 6)) m &= mask_le(hi & 63);
      int base2 = wpre64[prebase + w];
      while (m) {
        int bb = (int)__ffsll(m) - 1;
        m &= m - 1;
        int j = base2 + (int)__popcll(Rp[w] & mask_lt(bb));
        unite(suf, i, j);
      }
    }
  }
  __syncthreads();

  // P4: root bitmask over run ids (parent==self ballot), compact prefix.
  for (int j = 0; j < 4; j++) {
    int i = tid + (j << 9);
    unsigned long long bal = __ballot(i < nr && suf[i] == i);
    if (lane == 0) rootm[wv + (j << 3)] = bal;
  }
  __syncthreads();
  if (tid < 32) {
    int pc = (int)__popcll(rootm[tid]);
    int sa = pc;
    for (int off = 1; off < 32; off <<= 1) {
      int t = __shfl_up(sa, off);
      if (tid >= off) sa += t;
    }
    rpre[tid] = sa - pc;
  }
  __syncthreads();

  // P5: per-run stats. Read-check before min/max atomics (skip no-op RMWs on
  // the contended giant-component slot); only the area add is unconditional.
  for (int i = tid; i < nr; i += 512) {
    int root = find_halve(suf, i);
    int id = cid(rootm, rpre, root);
    int sp = sspan[i];
    int row = sp >> 16, a = (sp >> 8) & 255, b = sp & 255;
    atomicAdd(&sA[id], b - a + 1);
    if (a < sW0[id]) atomicMin(&sW0[id], a);
    if (b > sW1[id]) atomicMax(&sW1[id], b);
    if (row < sH0[id]) atomicMin(&sH0[id], row);
    if (row > sH1[id]) atomicMax(&sH1[id], row);
  }
  __syncthreads();

  // P6a: emit compact root records.
  int nc = rpre[31] + (int)__popcll(rootm[31]);
  for (int i = tid; i < nr; i += 512) {
    if (suf[i] == i) {
      int id = cid(rootm, rpre, i);
      int gid = (lm << 14) + (tile << 10) + id;
      int sp = sspan[i];
      gp[gid] = gid;
      ga[gid] = sA[id];
      gl[gid] = (unsigned short)((tile << 12) + ((sp >> 16) << 8) +
                                 ((sp >> 8) & 255));
      gbb[gid] = ((unsigned)(R0 + sH0[id]) << 24) | ((unsigned)sW0[id] << 16)
               | ((unsigned)(R0 + sH1[id]) << 8) | (unsigned)sW1[id];
    }
  }
  // P6b: boundary maps (1 boundary px/thread: 2 rows x 256 cols).
  {
    int c = tid & 255, topbot = tid >> 8;
    int brow = topbot ? (TRR - 1) : 0;
    unsigned short val = 0xFFFF;
    if ((sfgw[brow][c >> 6] >> (c & 63)) & 1) {
      int w = c >> 6, bb = c & 63;
      int id = wpre64[(brow << 2) + w] +
               (int)__popcll(srs[brow][w] & mask_le(bb)) - 1;
      int root = find_halve(suf, id);
      val = (unsigned short)((tile << 10) + cid(rootm, rpre, root));
    }
    gbrow[(q << 9) + (topbot ? 256 : 0) + c] = val;
  }
  if (tid == 0) gnr[q] = nc;

  // P7: bg bbox (thread = column c, half the rows) + dsum reductions.
  int c = tid & 255, half = (tid >> 8) << 3;
  int bh0r = TRR, bh1r = -1;
  bool anybg = false;
  for (int row = half; row < half + 8; row++) {
    if (!((sfgw[row][c >> 6] >> (c & 63)) & 1)) {
      anybg = true;
      bh0r = min(bh0r, row); bh1r = max(bh1r, row);
    }
  }
  int bw0r = anybg ? c : WW, bw1r = anybg ? c : -1;
  for (int off = 32; off > 0; off >>= 1) {
    bw0r = min(bw0r, __shfl_down(bw0r, off));
    bw1r = max(bw1r, __shfl_down(bw1r, off));
    bh0r = min(bh0r, __shfl_down(bh0r, off));
    bh1r = max(bh1r, __shfl_down(bh1r, off));
  }
  if (lane == 0) { sbb[0][wv] = bw0r; sbb[1][wv] = bw1r;
                   sbb[2][wv] = bh0r; sbb[3][wv] = bh1r; }
  for (int off = 32; off > 0; off >>= 1) dsum += __shfl_down(dsum, off);
  if (lane == 0) sred[wv] = dsum;
  __syncthreads();
  if (tid == 0) {
    int a0 = sbb[0][0], a1 = sbb[1][0], a2 = sbb[2][0], a3 = sbb[3][0];
    for (int i = 1; i < 8; i++) {
      a0 = min(a0, sbb[0][i]); a1 = max(a1, sbb[1][i]);
      a2 = min(a2, sbb[2][i]); a3 = max(a3, sbb[3][i]);
    }
    if (a1 >= 0) {
      atomicMin(&mt->bw0[gm], a0); atomicMax(&mt->bw1[gm], a1);
      atomicMin(&mt->bh0[gm], R0 + a2); atomicMax(&mt->bh1[gm], R0 + a3);
    }
    double t = 0.0;
    for (int i = 0; i < 8; i++) t += sred[i];
    atomicAdd(&mt->dsum[gm], t);
    if (tile == 0) mt->fg0[gm] = (int)(sfgw[0][0] & 1ull);
  }
}

// One block per seam (cn*15 blocks): unions on compact ids.
__global__ void k_seam(int* __restrict__ gp,
                       const unsigned short* __restrict__ gbrow) {
  int b = blockIdx.x;
  int lm = b / 15, s = b % 15;
  int tb = lm << 4;
  int sbase = lm << 14;
  const unsigned short* up = gbrow + ((tb + s) << 9) + 256;
  const unsigned short* lo = gbrow + ((tb + s + 1) << 9);
  int c = threadIdx.x;
  unsigned short v16 = lo[c];
  if (v16 == 0xFFFF) return;
  int v = sbase + v16;
  bool wfg = (c > 0) && (lo[c - 1] != 0xFFFF);
  unsigned short n16 = up[c];
  if (!wfg) {
    if (n16 != 0xFFFF) unite(gp, v, sbase + n16);
    else if (c > 0 && up[c - 1] != 0xFFFF) unite(gp, v, sbase + up[c - 1]);
  }
  if (n16 == 0xFFFF && c < 255 && up[c + 1] != 0xFFFF)
    unite(gp, v, sbase + up[c + 1]);
}

// One block per mask: wave-aggregated area push -> exact top-2 -> bbox sweep.
__global__ __launch_bounds__(1024)
void k_mask(int* __restrict__ gp, int* __restrict__ ga,
            const unsigned int* __restrict__ gbb,
            const unsigned short* __restrict__ gl,
            const int* __restrict__ gnr, Meta* __restrict__ mt, int c0) {
  int lm = blockIdx.x, gm = c0 + lm;
  int tid = threadIdx.x;
  int tb = lm << 4;
  int sbase = lm << 14;
  int wv = tid >> 6, lane = tid & 63;

  // Phase B: push areas of non-final roots into final roots, one atomic per
  // distinct root per wave (the giant component otherwise serializes ~3000
  // same-address global atomics per mask).
  for (int t = 0; t < SPM / 1024; t++) {
    int s = (t << 10) + tid;
    int r = -1, a = 0;
    if ((s & (SPT - 1)) < gnr[tb + (s >> 10)]) {
      int gid = sbase + s;
      int rr = find_c(gp, gid);
      if (rr != gid) { r = rr; a = ga[gid]; }
    }
    bool pend = (r >= 0);
    while (__any(pend)) {
      unsigned long long mk = __ballot(pend);
      int srcl = (int)__ffsll(mk) - 1;
      int lead = __shfl(r, srcl);
      bool mine = pend && (r == lead);
      int v = mine ? a : 0;
      for (int off = 32; off > 0; off >>= 1) v += __shfl_down(v, off);
      int tot = __shfl(v, 0);
      if (lane == srcl) atomicAdd(&ga[lead], tot);
      pend = pend && !mine;
    }
  }
  __syncthreads();

  // Phase C: top-2 with exact lax.top_k candidate set.
  // key = (area<<37)|((SS-lab)<<20)|slot : (area desc, label asc).
  unsigned long long t1 = 0, t2 = 0;
  int fsum = 0;
  for (int s = tid; s < SPM; s += 1024) {
    if ((s & (SPT - 1)) >= gnr[tb + (s >> 10)]) continue;
    int gid = sbase + s;
    if (gp[gid] == gid) {
      int a = ga[gid];
      int lab = gl[gid];
      fsum += a;
      unsigned long long key = ((unsigned long long)a << 37)
                             | ((unsigned long long)(SS - lab) << 20)
                             | (unsigned)s;
      if (key > t1) { t2 = t1; t1 = key; }
      else if (key > t2) t2 = key;
    }
  }
  for (int off = 32; off > 0; off >>= 1) {
    unsigned long long o1 = __shfl_down(t1, off), o2 = __shfl_down(t2, off);
    if (o1 > t1) { t2 = (t1 > o2) ? t1 : o2; t1 = o1; }
    else if (o1 > t2) t2 = o1;
    fsum += __shfl_down(fsum, off);
  }
  __shared__ unsigned long long s1[16], s2[16];
  __shared__ int sf[16];
  __shared__ int ssel, sslot;
  if (lane == 0) { s1[wv] = t1; s2[wv] = t2; sf[wv] = fsum; }
  __syncthreads();
  if (tid == 0) {
    t1 = s1[0]; t2 = s2[0]; fsum = sf[0];
    for (int i = 1; i < 16; i++) {
      unsigned long long o1 = s1[i], o2 = s2[i];
      if (o1 > t1) { t2 = (t1 > o2) ? t1 : o2; t1 = o1; }
      else if (o1 > t2) t2 = o1;
      fsum += sf[i];
    }
    unsigned long long bg = ((unsigned long long)(SS - fsum)) << 37;
    int zl = mt->fg0[gm] ? 1 : 0;   // best zero-area label (R5/R7 proof)
    unsigned long long zk = ((unsigned long long)(SS - zl)) << 20;
    if (bg > t1) { t2 = t1; t1 = bg; } else if (bg > t2) t2 = bg;
    if (zk > t1) { t2 = t1; t1 = zk; } else if (zk > t2) t2 = zk;
    if (t2 == bg) {
      ssel = 1;
      mt->h0[gm] = mt->bh0[gm]; mt->h1[gm] = mt->bh1[gm];
      mt->w0[gm] = mt->bw0[gm]; mt->w1[gm] = mt->bw1[gm];
    } else if (t2 == zk) {
      ssel = 2;
      mt->h0[gm] = 1; mt->h1[gm] = 0; mt->w0[gm] = 1; mt->w1[gm] = 0;
    } else {
      ssel = 0; sslot = (int)(t2 & 0xFFFFF);
    }
  }
  __syncthreads();

  // Phase D: union the packed bboxes of all slots in the chosen component.
  if (ssel == 0) {
    int secgid = sbase + sslot;
    int h0l = HH, h1l = -1, w0l = WW, w1l = -1;
    for (int s = tid; s < SPM; s += 1024) {
      if ((s & (SPT - 1)) >= gnr[tb + (s >> 10)]) continue;
      int i = sbase + s;
      if (find_c(gp, i) == secgid) {
        unsigned int bb = gbb[i];
        h0l = min(h0l, (int)(bb >> 24));
        w0l = min(w0l, (int)((bb >> 16) & 255));
        h1l = max(h1l, (int)((bb >> 8) & 255));
        w1l = max(w1l, (int)(bb & 255));
      }
    }
    for (int off = 32; off > 0; off >>= 1) {
      h0l = min(h0l, __shfl_down(h0l, off));
      w0l = min(w0l, __shfl_down(w0l, off));
      h1l = max(h1l, __shfl_down(h1l, off));
      w1l = max(w1l, __shfl_down(w1l, off));
    }
    __shared__ int r0[16], r1[16], r2[16], r3[16];
    if (lane == 0) { r0[wv] = h0l; r1[wv] = h1l; r2[wv] = w0l; r3[wv] = w1l; }
    __syncthreads();
    if (tid == 0) {
      for (int i = 1; i < 16; i++) {
        r0[0] = min(r0[0], r0[i]); r1[0] = max(r1[0], r1[i]);
        r2[0] = min(r2[0], r2[i]); r3[0] = max(r3[0], r3[i]);
      }
      mt->h0[gm] = r0[0]; mt->h1[gm] = r1[0];
      mt->w0[gm] = r2[0]; mt->w1[gm] = r3[0];
    }
  }
}

// 8 blocks per mask over the bbox rows; double partials into dins.
__global__ void k_inside(const float* __restrict__ in, Meta* __restrict__ mt,
                         int c0) {
  int b = blockIdx.x;
  int lm = b >> 3, seg = b & 7;
  int gm = c0 + lm;
  int h0 = mt->h0[gm], h1 = mt->h1[gm], w0 = mt->w0[gm], w1 = mt->w1[gm];
  double acc = 0.0;
  if (h1 >= h0) {
    int cc = w0 + threadIdx.x;
    if (cc <= w1) {
      const float* base = in + ((size_t)gm << 16);
      for (int rr = h0 + seg; rr <= h1; rr += 8) {
        float x = base[(rr << 8) + cc];
        acc += (double)fmaxf((x + 1.0f) * 0.5f, 0.0f);
      }
    }
  }
  for (int off = 32; off > 0; off >>= 1) acc += __shfl_down(acc, off);
  __shared__ double sd[4];
  int wid = threadIdx.x >> 6, lane = threadIdx.x & 63;
  if (lane == 0) sd[wid] = acc;
  __syncthreads();
  if (threadIdx.x == 0) {
    double t = sd[0] + sd[1] + sd[2] + sd[3];
    if (t != 0.0) atomicAdd(&mt->dins[gm], t);
  }
}

__global__ void k_final(const Meta* __restrict__ mt, float* __restrict__ out) {
  __shared__ double sd[NM];
  int t = threadIdx.x;
  sd[t] = (mt->dsum[t] - mt->dins[t]) / (double)SS;
  __syncthreads();
  for (int off = 64; off > 0; off >>= 1) {
    if (t < off) sd[t] += sd[t + off];
    __syncthreads();
  }
  if (t == 0) out[0] = (float)(sd[0] / (double)NM);
}

extern "C" void kernel_launch(void* const* d_in, const int* in_sizes, int n_in,
                              void* d_out, int out_size, void* d_ws,
                              size_t ws_size, hipStream_t stream) {
  const float* in = (const float*)d_in[0];
  float* out = (float*)d_out;

  Meta* mt = (Meta*)d_ws;
  const size_t meta_bytes = (sizeof(Meta) + 255) & ~(size_t)255;
  char* base = (char*)d_ws + meta_bytes;
  size_t avail = (ws_size > meta_bytes) ? (ws_size - meta_bytes) : 0;
  const size_t per_mask =
      (size_t)SPM * (4 + 4 + 4 + 2) + (size_t)NT2 * 512 * 2 + NT2 * 4;
  int chunk = (int)(avail / per_mask);
  if (chunk > NM) chunk = NM;
  if (chunk < 1) return;  // insufficient workspace (would fail validation)

  char* ptr = base;
  int* gp = (int*)ptr;                 ptr += (size_t)chunk * SPM * 4;
  int* ga = (int*)ptr;                 ptr += (size_t)chunk * SPM * 4;
  unsigned int* gbb = (unsigned int*)ptr;       ptr += (size_t)chunk * SPM * 4;
  unsigned short* gl = (unsigned short*)ptr;    ptr += (size_t)chunk * SPM * 2;
  unsigned short* gbrow = (unsigned short*)ptr; ptr += (size_t)chunk * NT2 * 512 * 2;
  int* gnr = (int*)ptr;

  k_meta_init<<<1, 128, 0, stream>>>(mt);
  for (int c0 = 0; c0 < NM; c0 += chunk) {
    int cn = (chunk < NM - c0) ? chunk : (NM - c0);
    k_local<<<cn * NT2, 512, 0, stream>>>(in, c0, gp, ga, gbb, gl, gbrow,
                                          gnr, mt);
    k_seam <<<cn * 15, 256, 0, stream>>>(gp, gbrow);
    k_mask <<<cn, 1024, 0, stream>>>(gp, ga, gbb, gl, gnr, mt, c0);
    k_inside<<<cn * 8, 256, 0, stream>>>(in, mt, c0);
  }
  k_final<<<1, 128, 0, stream>>>(mt, out);
}